// Round 13
// baseline (55.094 us; speedup 1.0000x reference)
//
#include <hip/hip_runtime.h>
#include <hip/hip_fp16.h>
#include <stdint.h>

typedef float f32x4 __attribute__((ext_vector_type(4)));
typedef _Float16 f16x8 __attribute__((ext_vector_type(8)));
typedef unsigned short us8 __attribute__((ext_vector_type(8)));
typedef unsigned long long u64t;

#define EPS  3.0e-3f
#define FCAP 8192

// ws layout (bytes)
#define WS_TOKEN 0         // int[32768]
#define WS_BDIST 131072    // float[32768]
#define WS_PCB   262144    // ushort[65536] fp16 frag-linear codebook
#define WS_CBT   393216    // float[65536] cb transposed [d][c]
#define WS_C2    655360    // float[1024]
#define WS_MIND  659456    // u32[1024]
#define WS_ACT   663552    // int[1024]
#define WS_FLAG  667648    // int[8192]
#define WS_FCNT  700416    // u32[64]
#define WS_DPART 700672    // float[128]

__device__ __forceinline__ float hi_f(u64t v) {
    return __uint_as_float((unsigned)(v >> 32));
}

// ---------------- k0: init + fp16 frag-linear codebook + cbT + c2 ----------------
__global__ __launch_bounds__(256) void vq_k0(const float* __restrict__ cb,
                                             unsigned* __restrict__ minDist,
                                             int* __restrict__ active,
                                             float* __restrict__ c2,
                                             unsigned short* __restrict__ pcb,
                                             float* __restrict__ cbT,
                                             unsigned* __restrict__ fcnt) {
    int g = blockIdx.x * 256 + threadIdx.x;   // grid 64 -> 16384
    if (g < 64) fcnt[g] = 0;
    if (g < 1024) {
        active[g] = 0;
        minDist[g] = 0x7F800000u;   // +inf bits
        const float4* row = (const float4*)(cb + g * 64);
        float s = 0.f;
#pragma unroll
        for (int q = 0; q < 16; ++q) {
            float4 v = row[q];
            s = fmaf(v.x, v.x, s); s = fmaf(v.y, v.y, s);
            s = fmaf(v.z, v.z, s); s = fmaf(v.w, v.w, s);
        }
        c2[g] = s;
    }
    if (g < 8192) {   // fp16 frag-linear: unit = (code c, 8-elem d-chunk u)
        int c = g >> 3, u = g & 7;
        const float4* row = (const float4*)(cb + c * 64);
        float4 v0 = row[u * 2], v1 = row[u * 2 + 1];
        us8 o;
        o[0] = __half_as_ushort(__float2half_rn(v0.x));
        o[1] = __half_as_ushort(__float2half_rn(v0.y));
        o[2] = __half_as_ushort(__float2half_rn(v0.z));
        o[3] = __half_as_ushort(__float2half_rn(v0.w));
        o[4] = __half_as_ushort(__float2half_rn(v1.x));
        o[5] = __half_as_ushort(__float2half_rn(v1.y));
        o[6] = __half_as_ushort(__float2half_rn(v1.z));
        o[7] = __half_as_ushort(__float2half_rn(v1.w));
        int frag  = (c >> 4) * 2 + (u >> 2);
        int lane8 = (c & 15) + 16 * (u & 3);
        *(us8*)&pcb[frag * 512 + lane8 * 8] = o;
    }
    {   // transpose: cbT[d][c] = cb[c][d]
        int c = g & 1023, seg = g >> 10;
        float4 v = ((const float4*)(cb + c * 64))[seg];
        cbT[(seg * 4 + 0) * 1024 + c] = v.x;
        cbT[(seg * 4 + 1) * 1024 + c] = v.y;
        cbT[(seg * 4 + 2) * 1024 + c] = v.z;
        cbT[(seg * 4 + 3) * 1024 + c] = v.w;
    }
}

// ---------------- k1: 256-thr block, 16 pts x full codebook (r12, verified clean) ----------------
__global__ __launch_bounds__(256, 4) void vq_k1(const float* __restrict__ x,
                                                const float* __restrict__ cb,
                                                const float* __restrict__ c2g,
                                                const unsigned short* __restrict__ pcb,
                                                int* __restrict__ token,
                                                float* __restrict__ bdist,
                                                int* __restrict__ active,
                                                int* __restrict__ gflag,
                                                unsigned* __restrict__ fcnt,
                                                float* __restrict__ outp) {
    __shared__ __align__(16) unsigned short aF[1024];   // 2KB: 16 pts fp16 frags
    __shared__ float x2s[16];
    __shared__ float wd[4][16];
    __shared__ int   wc[4][16];
    __shared__ float wm[4][16];
    __shared__ int   toksh[16];

    const int tid  = threadIdx.x;
    const int lane = tid & 63;
    const int w    = tid >> 6;       // wave = code quarter
    const int col  = lane & 15;
    const int rg   = lane >> 4;
    const int p0   = blockIdx.x * 16;

    if (tid < 128) {
        int r = tid >> 3, u = tid & 7;
        const float4* xr4 = (const float4*)(x + (size_t)(p0 + r) * 64) + u * 2;
        float4 v0 = xr4[0], v1 = xr4[1];
        float s = 0.f;
        s = fmaf(v0.x, v0.x, s); s = fmaf(v0.y, v0.y, s);
        s = fmaf(v0.z, v0.z, s); s = fmaf(v0.w, v0.w, s);
        s = fmaf(v1.x, v1.x, s); s = fmaf(v1.y, v1.y, s);
        s = fmaf(v1.z, v1.z, s); s = fmaf(v1.w, v1.w, s);
        s += __shfl_xor(s, 1);
        s += __shfl_xor(s, 2);
        s += __shfl_xor(s, 4);
        if (u == 0) x2s[r] = s;

        us8 o;
        o[0] = __half_as_ushort(__float2half_rn(v0.x));
        o[1] = __half_as_ushort(__float2half_rn(v0.y));
        o[2] = __half_as_ushort(__float2half_rn(v0.z));
        o[3] = __half_as_ushort(__float2half_rn(v0.w));
        o[4] = __half_as_ushort(__float2half_rn(v1.x));
        o[5] = __half_as_ushort(__float2half_rn(v1.y));
        o[6] = __half_as_ushort(__float2half_rn(v1.z));
        o[7] = __half_as_ushort(__float2half_rn(v1.w));
        int f = u >> 2;
        int l = r + 16 * (u & 3);
        *(us8*)&aF[f * 512 + l * 8] = o;
    }
    __syncthreads();   // b1

    f16x8 a0 = *(const f16x8*)&aF[lane * 8];
    f16x8 a1 = *(const f16x8*)&aF[512 + lane * 8];

    float    m1d[4], m2r[4];
    unsigned m1c[4];
#pragma unroll
    for (int i = 0; i < 4; ++i) { m1d[i] = 3.4e38f; m2r[i] = 3.4e38f; m1c[i] = 0; }

    const f16x8* pb = (const f16x8*)pcb;

#pragma unroll 4
    for (int t = 0; t < 16; ++t) {
        const int ct = w * 16 + t;
        f16x8 b0 = pb[(ct * 2 + 0) * 64 + lane];
        f16x8 b1 = pb[(ct * 2 + 1) * 64 + lane];
        f32x4 acc = (f32x4){0.f, 0.f, 0.f, 0.f};
        acc = __builtin_amdgcn_mfma_f32_16x16x32_f16(a0, b0, acc, 0, 0, 0);
        acc = __builtin_amdgcn_mfma_f32_16x16x32_f16(a1, b1, acc, 0, 0, 0);

        const unsigned cl  = (unsigned)(ct * 16 + col);
        const float    c2v = c2g[cl];
#pragma unroll
        for (int i = 0; i < 4; ++i) {
            float dp = fmaf(-2.0f, acc[i], c2v);
            float lose = dp < m1d[i] ? m1d[i] : dp;
            m2r[i] = fminf(m2r[i], lose);
            m1c[i] = dp < m1d[i] ? cl : m1c[i];
            m1d[i] = fminf(m1d[i], dp);
        }
    }

#pragma unroll
    for (int s = 1; s < 16; s <<= 1) {
#pragma unroll
        for (int i = 0; i < 4; ++i) {
            float    od  = __shfl_xor(m1d[i], s);
            unsigned oc  = (unsigned)__shfl_xor((int)m1c[i], s);
            float    om2 = __shfl_xor(m2r[i], s);
            bool lt = (od < m1d[i]) || (od == m1d[i] && oc < m1c[i]);
            float lose = lt ? m1d[i] : od;
            m2r[i] = fminf(fminf(m2r[i], om2), lose);
            if (lt) { m1d[i] = od; m1c[i] = oc; }
        }
    }
    if (col == 0) {
#pragma unroll
        for (int i = 0; i < 4; ++i) {
            int pr = rg * 4 + i;
            wd[w][pr] = m1d[i];
            wc[w][pr] = (int)m1c[i];
            wm[w][pr] = m2r[i];
        }
    }
    __syncthreads();   // b2

    if (tid < 16) {
        float bd = wd[0][tid]; int bc = wc[0][tid]; float m2 = wm[0][tid];
#pragma unroll
        for (int qq = 1; qq < 4; ++qq) {
            float od = wd[qq][tid]; int oc = wc[qq][tid]; float om2 = wm[qq][tid];
            bool lt = (od < bd) || (od == bd && oc < bc);
            float lose = lt ? bd : od;
            m2 = fminf(fminf(m2, om2), lose);
            if (lt) { bd = od; bc = oc; }
        }
        int p = p0 + tid;
        token[p]   = bc;
        toksh[tid] = bc;
        bdist[p]   = bd + x2s[tid];
        atomicAdd(&active[bc], 1);
        if (m2 - bd <= EPS) {
            unsigned ix = atomicAdd(fcnt, 1u);
            if (ix < FCAP) gflag[ix] = p;
        }
    }
    __syncthreads();   // b3

    {
        int g   = blockIdx.x * 256 + tid;
        int pl  = tid >> 4, seg = tid & 15;
        int tok = toksh[pl];
        float4 xv = ((const float4*)x)[g];
        float4 cv = ((const float4*)cb)[tok * 16 + seg];
        float4 o;
        o.x = xv.x + (cv.x - xv.x);
        o.y = xv.y + (cv.y - xv.y);
        o.z = xv.z + (cv.z - xv.z);
        o.w = xv.w + (cv.w - xv.w);
        ((float4*)outp)[g] = o;
    }
}

// ---------------- kfix: exact fp32 rescan, ~1 flagged point per block ----------------
__global__ __launch_bounds__(256) void vq_kfix(const float* __restrict__ x,
                                               const float* __restrict__ cb,
                                               const float* __restrict__ cbT,
                                               const float* __restrict__ c2,
                                               const int* __restrict__ gflag,
                                               const unsigned* __restrict__ fcnt,
                                               int* __restrict__ token,
                                               float* __restrict__ bdist,
                                               int* __restrict__ active,
                                               float* __restrict__ outp) {
    __shared__ float xl[64];
    __shared__ u64t red[256];
    __shared__ u64t bestSh;
    const int tid = threadIdx.x;
    unsigned nf = fcnt[0]; if (nf > FCAP) nf = FCAP;

    for (unsigned fi = blockIdx.x; fi < nf; fi += gridDim.x) {   // grid 512: ~1 pt/block
        int p = gflag[fi];
        __syncthreads();
        if (tid < 64) xl[tid] = x[(size_t)p * 64 + tid];
        __syncthreads();
        float x2v = 0.f;   // exact x2: sequential fma, reference association
#pragma unroll
        for (int d = 0; d < 64; ++d) x2v = fmaf(xl[d], xl[d], x2v);
        float s0 = 0.f, s1 = 0.f, s2 = 0.f, s3 = 0.f;
#pragma unroll
        for (int d = 0; d < 64; ++d) {
            float xv = xl[d];
            s0 = fmaf(xv, cbT[d * 1024 +   0 + tid], s0);
            s1 = fmaf(xv, cbT[d * 1024 + 256 + tid], s1);
            s2 = fmaf(xv, cbT[d * 1024 + 512 + tid], s2);
            s3 = fmaf(xv, cbT[d * 1024 + 768 + tid], s3);
        }
        float d0 = (x2v - 2.f * s0) + c2[tid];
        float d1 = (x2v - 2.f * s1) + c2[tid + 256];
        float d2 = (x2v - 2.f * s2) + c2[tid + 512];
        float d3 = (x2v - 2.f * s3) + c2[tid + 768];
        u64t bb = ~0ull, pk;
        pk = ((u64t)__float_as_uint(d0) << 32) | (unsigned)(tid);       if (pk < bb) bb = pk;
        pk = ((u64t)__float_as_uint(d1) << 32) | (unsigned)(tid + 256); if (pk < bb) bb = pk;
        pk = ((u64t)__float_as_uint(d2) << 32) | (unsigned)(tid + 512); if (pk < bb) bb = pk;
        pk = ((u64t)__float_as_uint(d3) << 32) | (unsigned)(tid + 768); if (pk < bb) bb = pk;
        red[tid] = bb;
        __syncthreads();
        for (int s = 128; s > 0; s >>= 1) {
            if (tid < s) { u64t o = red[tid + s]; if (o < red[tid]) red[tid] = o; }
            __syncthreads();
        }
        if (tid == 0) {
            u64t b = red[0];
            bestSh = b;
            int newc = (int)(unsigned)(b & 0xFFFFFFFFu);
            int oldc = token[p];
            token[p] = newc;
            bdist[p] = hi_f(b);
            if (newc != oldc) {
                atomicAdd(&active[oldc], -1);
                atomicAdd(&active[newc], 1);
            }
        }
        __syncthreads();
        int newc = (int)(unsigned)(bestSh & 0xFFFFFFFFu);
        if (tid < 64) {   // patch the output row
            float xv = xl[tid];
            float cv = cb[(size_t)newc * 64 + tid];
            outp[(size_t)p * 64 + tid] = xv + (cv - xv);
        }
    }
}

// ---------------- kent: bdist partial sums + inactive-code min-dists ----------------
// grid 128 x 256 thr. Always: partial-sum 256 bdist values -> dpart[bx].
// Then: exact min-dist scan for the (expected ~0) inactive codes.
__global__ __launch_bounds__(256) void vq_kent(const float* __restrict__ x,
                                               const float* __restrict__ cb,
                                               const int* __restrict__ active,
                                               const float* __restrict__ bdist,
                                               unsigned* __restrict__ minDist,
                                               float* __restrict__ dpart) {
    __shared__ int      ilist[1024];
    __shared__ unsigned icnt;
    __shared__ float    redf[4];
    __shared__ float    redp[4];
    const int tid = threadIdx.x;
    const int lane = tid & 63;
    const int w = tid >> 6;

    // deterministic bdist partial (shfl tree within wave, then 4-way)
    {
        float v = bdist[blockIdx.x * 256 + tid];
        v += __shfl_xor(v, 1);  v += __shfl_xor(v, 2);  v += __shfl_xor(v, 4);
        v += __shfl_xor(v, 8);  v += __shfl_xor(v, 16); v += __shfl_xor(v, 32);
        if (lane == 0) redp[w] = v;
    }
    if (tid == 0) icnt = 0;
    __syncthreads();
    if (tid == 0) dpart[blockIdx.x] = ((redp[0] + redp[1]) + (redp[2] + redp[3]));

#pragma unroll
    for (int qq = 0; qq < 4; ++qq) {
        int c = qq * 256 + tid;
        if (active[c] == 0) { unsigned ix = atomicAdd(&icnt, 1u); ilist[ix] = c; }
    }
    __syncthreads();
    const unsigned ni = icnt;
    if (ni == 0) return;

    const int p = blockIdx.x * 256 + tid;
    f32x4 xr[16];
    const f32x4* xrow = (const f32x4*)(x + (size_t)p * 64);
#pragma unroll
    for (int i = 0; i < 16; ++i) xr[i] = xrow[i];

    for (unsigned k = 0; k < ni; ++k) {
        const int c = __builtin_amdgcn_readfirstlane(ilist[k]);
        const f32x4* crow = (const f32x4*)(cb + (size_t)c * 64);
        float s = 0.f;
#pragma unroll
        for (int i = 0; i < 16; ++i) {
            f32x4 d4 = xr[i] - crow[i];
            s = fmaf(d4.x, d4.x, s); s = fmaf(d4.y, d4.y, s);
            s = fmaf(d4.z, d4.z, s); s = fmaf(d4.w, d4.w, s);
        }
#pragma unroll
        for (int m = 1; m < 64; m <<= 1) s = fminf(s, __shfl_xor(s, m));
        if ((tid & 63) == 0) redf[tid >> 6] = s;
        __syncthreads();
        if (tid == 0) {
            float m = fminf(fminf(redf[0], redf[1]), fminf(redf[2], redf[3]));
            atomicMin(minDist + c, __float_as_uint(m));
        }
        __syncthreads();
    }
}

// ---------------- k3f: entropy + dpart sum + final loss ----------------
__global__ __launch_bounds__(1024) void vq_k3f(const unsigned* __restrict__ minDist,
                                               const int* __restrict__ active,
                                               const float* __restrict__ dpart,
                                               float* __restrict__ out_loss) {
    __shared__ double red[1024];
    __shared__ double entS;
    const int t = threadIdx.x;

    red[t] = (active[t] == 0) ? (double)__uint_as_float(minDist[t]) : 0.0;
    __syncthreads();
    for (int s = 512; s > 0; s >>= 1) {
        if (t < s) red[t] += red[t + s];
        __syncthreads();
    }
    if (t == 0) entS = red[0];
    __syncthreads();

    red[t] = (t < 128) ? (double)dpart[t] : 0.0;
    __syncthreads();
    for (int s = 512; s > 0; s >>= 1) {
        if (t < s) red[t] += red[t + s];
        __syncthreads();
    }
    if (t == 0) {
        double mean_sq = red[0] / (double)(32768ll * 64);
        double total = 1.25 * mean_sq + 0.01 * (entS / 1024.0);
        out_loss[0] = (float)total;
    }
}

extern "C" void kernel_launch(void* const* d_in, const int* in_sizes, int n_in,
                              void* d_out, int out_size, void* d_ws, size_t ws_size,
                              hipStream_t stream) {
    const float* x  = (const float*)d_in[0];
    const float* cb = (const float*)d_in[1];
    float* out = (float*)d_out;
    char* ws = (char*)d_ws;

    int*            token   = (int*)(ws + WS_TOKEN);
    float*          bdist   = (float*)(ws + WS_BDIST);
    unsigned short* pcb     = (unsigned short*)(ws + WS_PCB);
    float*          cbT     = (float*)(ws + WS_CBT);
    float*          c2      = (float*)(ws + WS_C2);
    unsigned*       minDist = (unsigned*)(ws + WS_MIND);
    int*            active  = (int*)(ws + WS_ACT);
    int*            gflag   = (int*)(ws + WS_FLAG);
    unsigned*       fcnt    = (unsigned*)(ws + WS_FCNT);
    float*          dpart   = (float*)(ws + WS_DPART);

    vq_k0  <<<64,   256, 0, stream>>>(cb, minDist, active, c2, pcb, cbT, fcnt);
    vq_k1  <<<2048, 256, 0, stream>>>(x, cb, c2, pcb, token, bdist,
                                      active, gflag, fcnt, out);
    vq_kfix<<<512,  256, 0, stream>>>(x, cb, cbT, c2, gflag, fcnt, token, bdist,
                                      active, out);
    vq_kent<<<128,  256, 0, stream>>>(x, cb, active, bdist, minDist, dpart);
    vq_k3f <<<1,   1024, 0, stream>>>(minDist, active, dpart, out + 2097152);
}

// Round 14
// 50.712 us; speedup vs baseline: 1.0864x; 1.0864x over previous
//
#include <hip/hip_runtime.h>
#include <hip/hip_fp16.h>
#include <stdint.h>

typedef float f32x4 __attribute__((ext_vector_type(4)));
typedef _Float16 f16x8 __attribute__((ext_vector_type(8)));
typedef unsigned short us8 __attribute__((ext_vector_type(8)));
typedef unsigned long long u64t;

#define EPS  3.0e-3f

// ws layout (bytes)
#define WS_PCB   0         // ushort[65536] fp16 frag-linear codebook (128KB)
#define WS_CBT   131072    // float[65536] cb transposed [d][c] (256KB)
#define WS_C2    393216    // float[1024]
#define WS_ACT   397312    // int[1024]
#define WS_DPART 401408    // float[2048]

__device__ __forceinline__ float hi_f(u64t v) {
    return __uint_as_float((unsigned)(v >> 32));
}

// ---------------- k0: init + fp16 frag-linear codebook + cbT + c2 ----------------
__global__ __launch_bounds__(256) void vq_k0(const float* __restrict__ cb,
                                             int* __restrict__ active,
                                             float* __restrict__ c2,
                                             unsigned short* __restrict__ pcb,
                                             float* __restrict__ cbT) {
    int g = blockIdx.x * 256 + threadIdx.x;   // grid 64 -> 16384
    if (g < 1024) {
        active[g] = 0;
        const float4* row = (const float4*)(cb + g * 64);
        float s = 0.f;
#pragma unroll
        for (int q = 0; q < 16; ++q) {
            float4 v = row[q];
            s = fmaf(v.x, v.x, s); s = fmaf(v.y, v.y, s);
            s = fmaf(v.z, v.z, s); s = fmaf(v.w, v.w, s);
        }
        c2[g] = s;
    }
    if (g < 8192) {   // fp16 frag-linear: unit = (code c, 8-elem d-chunk u)
        int c = g >> 3, u = g & 7;
        const float4* row = (const float4*)(cb + c * 64);
        float4 v0 = row[u * 2], v1 = row[u * 2 + 1];
        us8 o;
        o[0] = __half_as_ushort(__float2half_rn(v0.x));
        o[1] = __half_as_ushort(__float2half_rn(v0.y));
        o[2] = __half_as_ushort(__float2half_rn(v0.z));
        o[3] = __half_as_ushort(__float2half_rn(v0.w));
        o[4] = __half_as_ushort(__float2half_rn(v1.x));
        o[5] = __half_as_ushort(__float2half_rn(v1.y));
        o[6] = __half_as_ushort(__float2half_rn(v1.z));
        o[7] = __half_as_ushort(__float2half_rn(v1.w));
        int frag  = (c >> 4) * 2 + (u >> 2);
        int lane8 = (c & 15) + 16 * (u & 3);
        *(us8*)&pcb[frag * 512 + lane8 * 8] = o;
    }
    {   // transpose: cbT[d][c] = cb[c][d]
        int c = g & 1023, seg = g >> 10;
        float4 v = ((const float4*)(cb + c * 64))[seg];
        cbT[(seg * 4 + 0) * 1024 + c] = v.x;
        cbT[(seg * 4 + 1) * 1024 + c] = v.y;
        cbT[(seg * 4 + 2) * 1024 + c] = v.z;
        cbT[(seg * 4 + 3) * 1024 + c] = v.w;
    }
}

// ---------------- k1: 16 pts x full codebook + in-block exact rescore + ST output ----------------
// grid 2048 x 256 thr (4 waves). wave w: 16 pts x 256 codes. No token/bdist globals:
// outputs are `out`, `active`, and dpart[bid] (per-block loss partial).
__global__ __launch_bounds__(256, 4) void vq_k1(const float* __restrict__ x,
                                                const float* __restrict__ cb,
                                                const float* __restrict__ c2g,
                                                const unsigned short* __restrict__ pcb,
                                                const float* __restrict__ cbT,
                                                int* __restrict__ active,
                                                float* __restrict__ dpart,
                                                float* __restrict__ outp) {
    __shared__ __align__(16) unsigned short aF[1024];   // 2KB: 16 pts fp16 frags
    __shared__ float    x2s[16];
    __shared__ float    wd[4][16];
    __shared__ int      wc[4][16];
    __shared__ float    wm[4][16];
    __shared__ float    bdSh[16];
    __shared__ int      bcSh[16];
    __shared__ int      toksh[16];
    __shared__ int      flist[16];
    __shared__ unsigned nflag;
    __shared__ float    xl[64];
    __shared__ u64t     red[256];

    const int tid  = threadIdx.x;
    const int lane = tid & 63;
    const int w    = tid >> 6;       // wave = code quarter
    const int col  = lane & 15;
    const int rg   = lane >> 4;
    const int p0   = blockIdx.x * 16;

    if (tid == 0) nflag = 0;

    // stage x -> fp16 frag-linear LDS + x2 (threads 0-127; split-assoc x2, approx path only)
    if (tid < 128) {
        int r = tid >> 3, u = tid & 7;
        const float4* xr4 = (const float4*)(x + (size_t)(p0 + r) * 64) + u * 2;
        float4 v0 = xr4[0], v1 = xr4[1];
        float s = 0.f;
        s = fmaf(v0.x, v0.x, s); s = fmaf(v0.y, v0.y, s);
        s = fmaf(v0.z, v0.z, s); s = fmaf(v0.w, v0.w, s);
        s = fmaf(v1.x, v1.x, s); s = fmaf(v1.y, v1.y, s);
        s = fmaf(v1.z, v1.z, s); s = fmaf(v1.w, v1.w, s);
        s += __shfl_xor(s, 1);
        s += __shfl_xor(s, 2);
        s += __shfl_xor(s, 4);
        if (u == 0) x2s[r] = s;

        us8 o;
        o[0] = __half_as_ushort(__float2half_rn(v0.x));
        o[1] = __half_as_ushort(__float2half_rn(v0.y));
        o[2] = __half_as_ushort(__float2half_rn(v0.z));
        o[3] = __half_as_ushort(__float2half_rn(v0.w));
        o[4] = __half_as_ushort(__float2half_rn(v1.x));
        o[5] = __half_as_ushort(__float2half_rn(v1.y));
        o[6] = __half_as_ushort(__float2half_rn(v1.z));
        o[7] = __half_as_ushort(__float2half_rn(v1.w));
        int f = u >> 2;
        int l = r + 16 * (u & 3);
        *(us8*)&aF[f * 512 + l * 8] = o;
    }
    __syncthreads();   // b1: aF/x2s/nflag ready

    f16x8 a0 = *(const f16x8*)&aF[lane * 8];
    f16x8 a1 = *(const f16x8*)&aF[512 + lane * 8];

    float    m1d[4], m2r[4];
    unsigned m1c[4];
#pragma unroll
    for (int i = 0; i < 4; ++i) { m1d[i] = 3.4e38f; m2r[i] = 3.4e38f; m1c[i] = 0; }

    const f16x8* pb = (const f16x8*)pcb;

    // 16 tiles of 16 codes (wave's quarter, codes increasing per lane)
#pragma unroll 4
    for (int t = 0; t < 16; ++t) {
        const int ct = w * 16 + t;
        f16x8 b0 = pb[(ct * 2 + 0) * 64 + lane];
        f16x8 b1 = pb[(ct * 2 + 1) * 64 + lane];
        f32x4 acc = (f32x4){0.f, 0.f, 0.f, 0.f};
        acc = __builtin_amdgcn_mfma_f32_16x16x32_f16(a0, b0, acc, 0, 0, 0);
        acc = __builtin_amdgcn_mfma_f32_16x16x32_f16(a1, b1, acc, 0, 0, 0);

        const unsigned cl  = (unsigned)(ct * 16 + col);
        const float    c2v = c2g[cl];
#pragma unroll
        for (int i = 0; i < 4; ++i) {
            float dp = fmaf(-2.0f, acc[i], c2v);        // dist minus x2 (const per row)
            float lose = dp < m1d[i] ? m1d[i] : dp;
            m2r[i] = fminf(m2r[i], lose);
            m1c[i] = dp < m1d[i] ? cl : m1c[i];         // codes increase: ties keep old
            m1d[i] = fminf(m1d[i], dp);
        }
    }

    // butterfly across the 16 code-lanes (lexicographic, first-index tie-break)
#pragma unroll
    for (int s = 1; s < 16; s <<= 1) {
#pragma unroll
        for (int i = 0; i < 4; ++i) {
            float    od  = __shfl_xor(m1d[i], s);
            unsigned oc  = (unsigned)__shfl_xor((int)m1c[i], s);
            float    om2 = __shfl_xor(m2r[i], s);
            bool lt = (od < m1d[i]) || (od == m1d[i] && oc < m1c[i]);
            float lose = lt ? m1d[i] : od;
            m2r[i] = fminf(fminf(m2r[i], om2), lose);
            if (lt) { m1d[i] = od; m1c[i] = oc; }
        }
    }
    if (col == 0) {
#pragma unroll
        for (int i = 0; i < 4; ++i) {
            int pr = rg * 4 + i;
            wd[w][pr] = m1d[i];
            wc[w][pr] = (int)m1c[i];
            wm[w][pr] = m2r[i];
        }
    }
    __syncthreads();   // b2: wd/wc/wm complete

    // threads 0-15: merge the 4 quarters (lexicographic); flag near-ties
    if (tid < 16) {
        float bd = wd[0][tid]; int bc = wc[0][tid]; float m2 = wm[0][tid];
#pragma unroll
        for (int qq = 1; qq < 4; ++qq) {
            float od = wd[qq][tid]; int oc = wc[qq][tid]; float om2 = wm[qq][tid];
            bool lt = (od < bd) || (od == bd && oc < bc);
            float lose = lt ? bd : od;
            m2 = fminf(fminf(m2, om2), lose);
            if (lt) { bd = od; bc = oc; }
        }
        bdSh[tid] = bd + x2s[tid];   // full (approx) dist
        bcSh[tid] = bc;
        if (m2 - bd <= EPS) {        // near-tie: exact in-block resolution
            unsigned ix = atomicAdd(&nflag, 1u);
            flist[ix] = tid;
        }
    }
    __syncthreads();   // b3: flags/bdSh/bcSh ready

    // in-block exact fp32 rescore (reference-identical sequential-fma association)
    const unsigned nf = nflag;
    for (unsigned f = 0; f < nf; ++f) {
        const int pr = flist[f];
        if (tid < 64) xl[tid] = x[(size_t)(p0 + pr) * 64 + tid];
        __syncthreads();
        float x2v = 0.f;
#pragma unroll 8
        for (int d = 0; d < 64; ++d) x2v = fmaf(xl[d], xl[d], x2v);
        float s0 = 0.f, s1 = 0.f, s2 = 0.f, s3 = 0.f;
#pragma unroll 8
        for (int d = 0; d < 64; ++d) {
            float xv = xl[d];
            s0 = fmaf(xv, cbT[d * 1024 +   0 + tid], s0);
            s1 = fmaf(xv, cbT[d * 1024 + 256 + tid], s1);
            s2 = fmaf(xv, cbT[d * 1024 + 512 + tid], s2);
            s3 = fmaf(xv, cbT[d * 1024 + 768 + tid], s3);
        }
        float d0 = (x2v - 2.f * s0) + c2g[tid];
        float d1 = (x2v - 2.f * s1) + c2g[tid + 256];
        float d2 = (x2v - 2.f * s2) + c2g[tid + 512];
        float d3 = (x2v - 2.f * s3) + c2g[tid + 768];
        u64t bb = ~0ull, pk;
        pk = ((u64t)__float_as_uint(d0) << 32) | (unsigned)(tid);       if (pk < bb) bb = pk;
        pk = ((u64t)__float_as_uint(d1) << 32) | (unsigned)(tid + 256); if (pk < bb) bb = pk;
        pk = ((u64t)__float_as_uint(d2) << 32) | (unsigned)(tid + 512); if (pk < bb) bb = pk;
        pk = ((u64t)__float_as_uint(d3) << 32) | (unsigned)(tid + 768); if (pk < bb) bb = pk;
        red[tid] = bb;
        __syncthreads();
        for (int s = 128; s > 0; s >>= 1) {
            if (tid < s) { u64t o = red[tid + s]; if (o < red[tid]) red[tid] = o; }
            __syncthreads();
        }
        if (tid == 0) {
            u64t b = red[0];
            bcSh[pr] = (int)(unsigned)(b & 1023u);
            bdSh[pr] = hi_f(b);
        }
        __syncthreads();
    }

    // finalize: tokens/active + per-block loss partial (deterministic 16-lane shfl tree)
    if (tid < 16) {
        int bc = bcSh[tid];
        toksh[tid] = bc;
        atomicAdd(&active[bc], 1);
        float v = bdSh[tid];
        v += __shfl_xor(v, 1);
        v += __shfl_xor(v, 2);
        v += __shfl_xor(v, 4);
        v += __shfl_xor(v, 8);
        if (tid == 0) dpart[blockIdx.x] = v;
    }
    __syncthreads();   // b4: toksh ready

    // fused straight-through output: 16 pts x 16 float4 = 256 float4 (1/thread)
    {
        int g   = blockIdx.x * 256 + tid;
        int pl  = tid >> 4, seg = tid & 15;
        int tok = toksh[pl];
        float4 xv = ((const float4*)x)[g];
        float4 cv = ((const float4*)cb)[tok * 16 + seg];
        float4 o;
        o.x = xv.x + (cv.x - xv.x);
        o.y = xv.y + (cv.y - xv.y);
        o.z = xv.z + (cv.z - xv.z);
        o.w = xv.w + (cv.w - xv.w);
        ((float4*)outp)[g] = o;
    }
}

// ---------------- ktail: dpart sum + entropy (inactive codes ~never) + final loss ----------------
__global__ __launch_bounds__(1024) void vq_ktail(const float* __restrict__ x,
                                                 const float* __restrict__ cb,
                                                 const int* __restrict__ active,
                                                 const float* __restrict__ dpart,
                                                 float* __restrict__ out_loss) {
    __shared__ double   red[1024];
    __shared__ int      ilist[1024];
    __shared__ unsigned icnt;
    __shared__ float    fred[1024];
    __shared__ double   entSh;
    const int t = threadIdx.x;

    if (t == 0) icnt = 0;
    // distortion sum: 2048 partials, 2 per thread
    red[t] = (double)dpart[t] + (double)dpart[t + 1024];
    __syncthreads();
    for (int s = 512; s > 0; s >>= 1) {
        if (t < s) red[t] += red[t + s];
        __syncthreads();
    }
    const double distSum = red[0];

    // inactive-code list (expected empty: P(any inactive) ~ 1e-7)
    if (active[t] == 0) { unsigned ix = atomicAdd(&icnt, 1u); ilist[ix] = t; }
    __syncthreads();
    const unsigned ni = icnt;

    double entS = 0.0;
    for (unsigned k = 0; k < ni; ++k) {   // slow exact fallback, correctness-only path
        const int c = ilist[k];
        const f32x4* crow = (const f32x4*)(cb + (size_t)c * 64);
        f32x4 cr[16];
#pragma unroll
        for (int i = 0; i < 16; ++i) cr[i] = crow[i];
        float m = 3.4e38f;
        for (int p = t; p < 32768; p += 1024) {
            const f32x4* xrow = (const f32x4*)(x + (size_t)p * 64);
            float s = 0.f;
#pragma unroll
            for (int i = 0; i < 16; ++i) {
                f32x4 d4 = xrow[i] - cr[i];
                s = fmaf(d4.x, d4.x, s); s = fmaf(d4.y, d4.y, s);
                s = fmaf(d4.z, d4.z, s); s = fmaf(d4.w, d4.w, s);
            }
            m = fminf(m, s);
        }
        fred[t] = m;
        __syncthreads();
        for (int s = 512; s > 0; s >>= 1) {
            if (t < s) fred[t] = fminf(fred[t], fred[t + s]);
            __syncthreads();
        }
        if (t == 0) entSh = (k == 0 ? 0.0 : entSh) + (double)fred[0];
        __syncthreads();
    }
    if (ni > 0) { __syncthreads(); entS = entSh; }

    if (t == 0) {
        double mean_sq = distSum / (double)(32768ll * 64);
        double total = 1.25 * mean_sq + 0.01 * (entS / 1024.0);
        out_loss[0] = (float)total;
    }
}

extern "C" void kernel_launch(void* const* d_in, const int* in_sizes, int n_in,
                              void* d_out, int out_size, void* d_ws, size_t ws_size,
                              hipStream_t stream) {
    const float* x  = (const float*)d_in[0];
    const float* cb = (const float*)d_in[1];
    float* out = (float*)d_out;
    char* ws = (char*)d_ws;

    unsigned short* pcb    = (unsigned short*)(ws + WS_PCB);
    float*          cbT    = (float*)(ws + WS_CBT);
    float*          c2     = (float*)(ws + WS_C2);
    int*            active = (int*)(ws + WS_ACT);
    float*          dpart  = (float*)(ws + WS_DPART);

    vq_k0   <<<64,   256, 0, stream>>>(cb, active, c2, pcb, cbT);
    vq_k1   <<<2048, 256, 0, stream>>>(x, cb, c2, pcb, cbT, active, dpart, out);
    vq_ktail<<<1,   1024, 0, stream>>>(x, cb, active, dpart, out + 2097152);
}

// Round 15
// 48.591 us; speedup vs baseline: 1.1338x; 1.0436x over previous
//
#include <hip/hip_runtime.h>
#include <hip/hip_fp16.h>
#include <stdint.h>

typedef float f32x4 __attribute__((ext_vector_type(4)));
typedef _Float16 f16x8 __attribute__((ext_vector_type(8)));
typedef unsigned short us8 __attribute__((ext_vector_type(8)));
typedef unsigned long long u64t;

#define EPS  3.0e-3f
#define FCAP 8192

// ws layout (bytes)
#define WS_TOKEN 0         // int[32768]
#define WS_BDIST 131072    // float[32768]
#define WS_PCB   262144    // ushort[65536] fp16 frag-linear codebook
#define WS_CBT   393216    // float[65536] cb transposed [d][c]
#define WS_C2    655360    // float[1024]
#define WS_SHARD 659456    // u32[16*1024]
#define WS_ACT   724992    // int[1024]
#define WS_FLAG  729088    // int[8192]
#define WS_FCNT  761856    // u32[64]

__device__ __forceinline__ float hi_f(u64t v) {
    return __uint_as_float((unsigned)(v >> 32));
}

// ---------------- k0: init + fp16 frag-linear codebook + cbT + c2 ----------------
__global__ __launch_bounds__(256) void vq_k0(const float* __restrict__ cb,
                                             unsigned* __restrict__ shard,
                                             int* __restrict__ active,
                                             float* __restrict__ c2,
                                             unsigned short* __restrict__ pcb,
                                             float* __restrict__ cbT,
                                             unsigned* __restrict__ fcnt) {
    int g = blockIdx.x * 256 + threadIdx.x;   // grid 64 -> 16384
    shard[g] = 0x7F800000u;                   // 16*1024 entries
    if (g < 64) fcnt[g] = 0;
    if (g < 1024) {
        active[g] = 0;
        const float4* row = (const float4*)(cb + g * 64);
        float s = 0.f;
#pragma unroll
        for (int q = 0; q < 16; ++q) {
            float4 v = row[q];
            s = fmaf(v.x, v.x, s); s = fmaf(v.y, v.y, s);
            s = fmaf(v.z, v.z, s); s = fmaf(v.w, v.w, s);
        }
        c2[g] = s;
    }
    if (g < 8192) {   // fp16 frag-linear: unit = (code c, 8-elem d-chunk u)
        int c = g >> 3, u = g & 7;
        const float4* row = (const float4*)(cb + c * 64);
        float4 v0 = row[u * 2], v1 = row[u * 2 + 1];
        us8 o;
        o[0] = __half_as_ushort(__float2half_rn(v0.x));
        o[1] = __half_as_ushort(__float2half_rn(v0.y));
        o[2] = __half_as_ushort(__float2half_rn(v0.z));
        o[3] = __half_as_ushort(__float2half_rn(v0.w));
        o[4] = __half_as_ushort(__float2half_rn(v1.x));
        o[5] = __half_as_ushort(__float2half_rn(v1.y));
        o[6] = __half_as_ushort(__float2half_rn(v1.z));
        o[7] = __half_as_ushort(__float2half_rn(v1.w));
        int frag  = (c >> 4) * 2 + (u >> 2);
        int lane8 = (c & 15) + 16 * (u & 3);
        *(us8*)&pcb[frag * 512 + lane8 * 8] = o;
    }
    {   // transpose: cbT[d][c] = cb[c][d]
        int c = g & 1023, seg = g >> 10;
        float4 v = ((const float4*)(cb + c * 64))[seg];
        cbT[(seg * 4 + 0) * 1024 + c] = v.x;
        cbT[(seg * 4 + 1) * 1024 + c] = v.y;
        cbT[(seg * 4 + 2) * 1024 + c] = v.z;
        cbT[(seg * 4 + 3) * 1024 + c] = v.w;
    }
}

// ---------------- k1: 1024-thread block, 64 pts x full codebook, in-block merge,
//                      fused straight-through output ----------------
// grid 512 -> 2 blocks/CU -> 32 waves/CU. wave (pg = w&3: 16 pts, cq = w>>2: 256 codes).
__global__ __launch_bounds__(1024, 8) void vq_k1(const float* __restrict__ x,
                                                 const float* __restrict__ cb,
                                                 const float* __restrict__ c2g,
                                                 const unsigned short* __restrict__ pcb,
                                                 unsigned* __restrict__ shard,
                                                 int* __restrict__ token,
                                                 float* __restrict__ bdist,
                                                 int* __restrict__ active,
                                                 int* __restrict__ gflag,
                                                 unsigned* __restrict__ fcnt,
                                                 float* __restrict__ outp) {
    __shared__ __align__(16) unsigned short aF[4096];  // 8KB fp16 x-frags (64 pts)
    __shared__ float    c2s[1024];
    __shared__ unsigned mcode[1024];                   // block-wide per-code min (dist bits)
    __shared__ float    x2s[64];
    __shared__ float    wd[4][64];
    __shared__ int      wc[4][64];
    __shared__ float    wm[4][64];
    __shared__ int      toksh[64];

    const int tid  = threadIdx.x;
    const int lane = tid & 63;
    const int w    = tid >> 6;
    const int col  = lane & 15;
    const int rg   = lane >> 4;
    const int pg   = w & 3;        // point group (16 pts)
    const int cq   = w >> 2;       // code quarter (256 codes)
    const int p0   = blockIdx.x * 64;

    // stage x -> fp16 frag-linear LDS + x2 (threads 0-255, as verified in r5/r6)
    if (tid < 256) {
        int r = tid >> 2, sg = tid & 3;
        const float4* xr4 = (const float4*)(x + (size_t)(p0 + r) * 64) + sg * 4;
        float4 v0 = xr4[0], v1 = xr4[1], v2 = xr4[2], v3 = xr4[3];
        float s = 0.f;
        s = fmaf(v0.x, v0.x, s); s = fmaf(v0.y, v0.y, s); s = fmaf(v0.z, v0.z, s); s = fmaf(v0.w, v0.w, s);
        s = fmaf(v1.x, v1.x, s); s = fmaf(v1.y, v1.y, s); s = fmaf(v1.z, v1.z, s); s = fmaf(v1.w, v1.w, s);
        s = fmaf(v2.x, v2.x, s); s = fmaf(v2.y, v2.y, s); s = fmaf(v2.z, v2.z, s); s = fmaf(v2.w, v2.w, s);
        s = fmaf(v3.x, v3.x, s); s = fmaf(v3.y, v3.y, s); s = fmaf(v3.z, v3.z, s); s = fmaf(v3.w, v3.w, s);
        s += __shfl_xor(s, 1);
        s += __shfl_xor(s, 2);
        if (sg == 0) x2s[r] = s;

        us8 o0, o1;
        o0[0]=__half_as_ushort(__float2half_rn(v0.x)); o0[1]=__half_as_ushort(__float2half_rn(v0.y));
        o0[2]=__half_as_ushort(__float2half_rn(v0.z)); o0[3]=__half_as_ushort(__float2half_rn(v0.w));
        o0[4]=__half_as_ushort(__float2half_rn(v1.x)); o0[5]=__half_as_ushort(__float2half_rn(v1.y));
        o0[6]=__half_as_ushort(__float2half_rn(v1.z)); o0[7]=__half_as_ushort(__float2half_rn(v1.w));
        o1[0]=__half_as_ushort(__float2half_rn(v2.x)); o1[1]=__half_as_ushort(__float2half_rn(v2.y));
        o1[2]=__half_as_ushort(__float2half_rn(v2.z)); o1[3]=__half_as_ushort(__float2half_rn(v2.w));
        o1[4]=__half_as_ushort(__float2half_rn(v3.x)); o1[5]=__half_as_ushort(__float2half_rn(v3.y));
        o1[6]=__half_as_ushort(__float2half_rn(v3.z)); o1[7]=__half_as_ushort(__float2half_rn(v3.w));
        int u0 = 2 * sg, u1 = 2 * sg + 1;
        int f0 = (r >> 4) * 2 + (u0 >> 2), l0 = (r & 15) + 16 * (u0 & 3);
        int f1 = (r >> 4) * 2 + (u1 >> 2), l1 = (r & 15) + 16 * (u1 & 3);
        *(us8*)&aF[f0 * 512 + l0 * 8] = o0;
        *(us8*)&aF[f1 * 512 + l1 * 8] = o1;
    }
    c2s[tid]   = c2g[tid];
    mcode[tid] = 0x7F800000u;
    __syncthreads();   // barrier #1: aF/x2s/c2s/mcode ready

    f16x8 a0 = *(const f16x8*)&aF[(pg * 2 + 0) * 512 + lane * 8];
    f16x8 a1 = *(const f16x8*)&aF[(pg * 2 + 1) * 512 + lane * 8];

    float x2r[4];
#pragma unroll
    for (int i = 0; i < 4; ++i) x2r[i] = x2s[pg * 16 + rg * 4 + i];

    float    m1d[4], m2r[4];
    unsigned m1c[4];
#pragma unroll
    for (int i = 0; i < 4; ++i) { m1d[i] = 3.4e38f; m2r[i] = 3.4e38f; m1c[i] = 0; }

    const f16x8* pb = (const f16x8*)pcb;

    // main loop: 16 tiles of 16 codes (this wave's quarter), shuffle-free epilogue
#pragma unroll 8
    for (int t = 0; t < 16; ++t) {
        const int ct = cq * 16 + t;                     // global code-tile
        f16x8 b0 = pb[(ct * 2 + 0) * 64 + lane];
        f16x8 b1 = pb[(ct * 2 + 1) * 64 + lane];
        f32x4 acc = (f32x4){0.f, 0.f, 0.f, 0.f};
        acc = __builtin_amdgcn_mfma_f32_16x16x32_f16(a0, b0, acc, 0, 0, 0);
        acc = __builtin_amdgcn_mfma_f32_16x16x32_f16(a1, b1, acc, 0, 0, 0);

        const int   cl  = ct * 16 + col;                // global code
        const float c2v = c2s[cl];
        float fl[4];
#pragma unroll
        for (int i = 0; i < 4; ++i) {
            float dp = fmaf(-2.0f, acc[i], c2v);        // dist minus x2 (const per row)
            float lose = dp < m1d[i] ? m1d[i] : dp;
            m2r[i] = fminf(m2r[i], lose);
            m1c[i] = dp < m1d[i] ? (unsigned)cl : m1c[i];   // codes increase: ties keep old
            m1d[i] = fminf(m1d[i], dp);
            fl[i] = dp + x2r[i];                        // full dist for per-code min
        }
        float pf = fminf(fminf(fl[0], fl[1]), fminf(fl[2], fl[3]));
        atomicMin(&mcode[cl], __float_as_uint(pf));     // ds_min no-return, off critical path
    }

    // butterfly across the 16 code-lanes (lexicographic, first-index tie-break)
#pragma unroll
    for (int s = 1; s < 16; s <<= 1) {
#pragma unroll
        for (int i = 0; i < 4; ++i) {
            float    od  = __shfl_xor(m1d[i], s);
            unsigned oc  = (unsigned)__shfl_xor((int)m1c[i], s);
            float    om2 = __shfl_xor(m2r[i], s);
            bool lt = (od < m1d[i]) || (od == m1d[i] && oc < m1c[i]);
            float lose = lt ? m1d[i] : od;
            m2r[i] = fminf(fminf(m2r[i], om2), lose);
            if (lt) { m1d[i] = od; m1c[i] = oc; }
        }
    }
    if (col == 0) {
#pragma unroll
        for (int i = 0; i < 4; ++i) {
            int pr = pg * 16 + rg * 4 + i;
            wd[cq][pr] = m1d[i];
            wc[cq][pr] = (int)m1c[i];
            wm[cq][pr] = m2r[i];
        }
    }
    __syncthreads();   // barrier #2: wred + mcode complete

    // threads 0-63: merge the 4 quarters (ascending -> lowest-code tie-break)
    if (tid < 64) {
        float bd = wd[0][tid]; int bc = wc[0][tid]; float m2 = wm[0][tid];
#pragma unroll
        for (int q = 1; q < 4; ++q) {
            float od = wd[q][tid]; int oc = wc[q][tid]; float om2 = wm[q][tid];
            float lose = od < bd ? bd : od;
            m2 = fminf(fminf(m2, om2), lose);
            if (od < bd) { bd = od; bc = oc; }
        }
        int p = p0 + tid;
        token[p]   = bc;
        toksh[tid] = bc;
        bdist[p]   = bd + x2s[tid];
        atomicAdd(&active[bc], 1);
        if (m2 - bd <= EPS) {                 // near-tie: exact resolution needed
            unsigned ix = atomicAdd(fcnt, 1u);
            if (ix < FCAP) gflag[ix] = p;
        }
    }
    {   // flush block per-code mins to sharded global (1 atomic/thread)
        atomicMin(&shard[(blockIdx.x & 15) * 1024 + tid], mcode[tid]);
    }
    __syncthreads();   // barrier #3: toksh ready

    // fused straight-through output: 64 pts x 16 float4 = 1024 float4 (1/thread)
    {
        int g  = blockIdx.x * 1024 + tid;     // global float4 index
        int pl = tid >> 4, q = tid & 15;
        int tok = toksh[pl];
        float4 xv = ((const float4*)x)[g];
        float4 cv = ((const float4*)cb)[tok * 16 + q];
        float4 o;
        o.x = xv.x + (cv.x - xv.x);
        o.y = xv.y + (cv.y - xv.y);
        o.z = xv.z + (cv.z - xv.z);
        o.w = xv.w + (cv.w - xv.w);
        ((float4*)outp)[g] = o;
    }
}

// ---------------- kfix: exact fp32 rescan for flagged points (+fix out/active) ----------------
__global__ __launch_bounds__(256) void vq_kfix(const float* __restrict__ x,
                                               const float* __restrict__ cb,
                                               const float* __restrict__ cbT,
                                               const float* __restrict__ c2,
                                               const int* __restrict__ gflag,
                                               const unsigned* __restrict__ fcnt,
                                               int* __restrict__ token,
                                               float* __restrict__ bdist,
                                               int* __restrict__ active,
                                               float* __restrict__ outp) {
    __shared__ float xl[64];
    __shared__ u64t red[256];
    __shared__ u64t bestSh;
    const int tid = threadIdx.x;
    unsigned nf = fcnt[0]; if (nf > FCAP) nf = FCAP;

    for (unsigned fi = blockIdx.x; fi < nf; fi += gridDim.x) {   // grid 256
        int p = gflag[fi];
        __syncthreads();
        if (tid < 64) xl[tid] = x[(size_t)p * 64 + tid];
        __syncthreads();
        float x2v = 0.f;   // exact x2: sequential fma, reference association
#pragma unroll
        for (int d = 0; d < 64; ++d) x2v = fmaf(xl[d], xl[d], x2v);
        float s0 = 0.f, s1 = 0.f, s2 = 0.f, s3 = 0.f;
#pragma unroll
        for (int d = 0; d < 64; ++d) {
            float xv = xl[d];
            s0 = fmaf(xv, cbT[d * 1024 +   0 + tid], s0);
            s1 = fmaf(xv, cbT[d * 1024 + 256 + tid], s1);
            s2 = fmaf(xv, cbT[d * 1024 + 512 + tid], s2);
            s3 = fmaf(xv, cbT[d * 1024 + 768 + tid], s3);
        }
        float d0 = (x2v - 2.f * s0) + c2[tid];
        float d1 = (x2v - 2.f * s1) + c2[tid + 256];
        float d2 = (x2v - 2.f * s2) + c2[tid + 512];
        float d3 = (x2v - 2.f * s3) + c2[tid + 768];
        u64t bb = ~0ull, pk;
        pk = ((u64t)__float_as_uint(d0) << 32) | (unsigned)(tid);       if (pk < bb) bb = pk;
        pk = ((u64t)__float_as_uint(d1) << 32) | (unsigned)(tid + 256); if (pk < bb) bb = pk;
        pk = ((u64t)__float_as_uint(d2) << 32) | (unsigned)(tid + 512); if (pk < bb) bb = pk;
        pk = ((u64t)__float_as_uint(d3) << 32) | (unsigned)(tid + 768); if (pk < bb) bb = pk;
        red[tid] = bb;
        __syncthreads();
        for (int s = 128; s > 0; s >>= 1) {
            if (tid < s) { u64t o = red[tid + s]; if (o < red[tid]) red[tid] = o; }
            __syncthreads();
        }
        if (tid == 0) {
            u64t b = red[0];
            bestSh = b;
            int newc = (int)(unsigned)(b & 0xFFFFFFFFu);
            int oldc = token[p];
            token[p] = newc;
            bdist[p] = hi_f(b);
            if (newc != oldc) {
                atomicAdd(&active[oldc], -1);
                atomicAdd(&active[newc], 1);
            }
        }
        __syncthreads();
        int newc = (int)(unsigned)(bestSh & 0xFFFFFFFFu);
        if (tid < 64) {   // patch the output row
            float xv = xl[tid];
            float cv = cb[(size_t)newc * 64 + tid];
            outp[(size_t)p * 64 + tid] = xv + (cv - xv);
        }
    }
}

// ---------------- k3f: shard merge + entropy + bdist sum + final loss ----------------
__global__ __launch_bounds__(1024) void vq_k3f(const unsigned* __restrict__ shard,
                                               const int* __restrict__ active,
                                               const float* __restrict__ bdist,
                                               float* __restrict__ out_loss) {
    __shared__ double red[1024];
    __shared__ double entS;
    const int t = threadIdx.x;

    unsigned m = 0x7F800000u;
#pragma unroll
    for (int s = 0; s < 16; ++s) m = min(m, shard[s * 1024 + t]);
    red[t] = (active[t] == 0) ? (double)__uint_as_float(m) : 0.0;
    __syncthreads();
    for (int s = 512; s > 0; s >>= 1) {
        if (t < s) red[t] += red[t + s];
        __syncthreads();
    }
    if (t == 0) entS = red[0];
    __syncthreads();

    double acc = 0.0;
#pragma unroll
    for (int k = 0; k < 32; ++k) acc += (double)bdist[k * 1024 + t];
    red[t] = acc;
    __syncthreads();
    for (int s = 512; s > 0; s >>= 1) {
        if (t < s) red[t] += red[t + s];
        __syncthreads();
    }
    if (t == 0) {
        double mean_sq = red[0] / (double)(32768ll * 64);
        double total = 1.25 * mean_sq + 0.01 * (entS / 1024.0);
        out_loss[0] = (float)total;
    }
}

extern "C" void kernel_launch(void* const* d_in, const int* in_sizes, int n_in,
                              void* d_out, int out_size, void* d_ws, size_t ws_size,
                              hipStream_t stream) {
    const float* x  = (const float*)d_in[0];
    const float* cb = (const float*)d_in[1];
    float* out = (float*)d_out;
    char* ws = (char*)d_ws;

    int*            token  = (int*)(ws + WS_TOKEN);
    float*          bdist  = (float*)(ws + WS_BDIST);
    unsigned short* pcb    = (unsigned short*)(ws + WS_PCB);
    float*          cbT    = (float*)(ws + WS_CBT);
    float*          c2     = (float*)(ws + WS_C2);
    unsigned*       shard  = (unsigned*)(ws + WS_SHARD);
    int*            active = (int*)(ws + WS_ACT);
    int*            gflag  = (int*)(ws + WS_FLAG);
    unsigned*       fcnt   = (unsigned*)(ws + WS_FCNT);

    vq_k0  <<<64,   256, 0, stream>>>(cb, shard, active, c2, pcb, cbT, fcnt);
    vq_k1  <<<512, 1024, 0, stream>>>(x, cb, c2, pcb, shard, token, bdist,
                                      active, gflag, fcnt, out);
    vq_kfix<<<256,  256, 0, stream>>>(x, cb, cbT, c2, gflag, fcnt, token, bdist,
                                      active, out);
    vq_k3f <<<1,   1024, 0, stream>>>(shard, active, bdist, out + 2097152);
}